// Round 1
// baseline (12458.708 us; speedup 1.0000x reference)
//
#include <hip/hip_runtime.h>
#include <math.h>

// MoE ViT forward, fp32 baseline.
// B=8, S=197, D=768, NH=12, HD=64, E=4, HID=3072, DEPTH=12, NC=1000

#define BB 8
#define SS 197
#define DD 768
#define MT (BB*SS)      // 1576 tokens
#define NPATCH 196
#define MPE (BB*NPATCH) // 1568
#define HHID 3072
#define NEXP 4

// ---------------- patch gather: Xp[m,k] = x[b,cin, py*16+ph, px*16+pw] ----------------
__global__ void gather_patches(const float* __restrict__ x, float* __restrict__ Xp) {
    int i = blockIdx.x * 256 + threadIdx.x;
    if (i >= MPE * DD) return;
    int k = i % DD;       // cin*256 + ph*16 + pw
    int m = i / DD;       // b*196 + py*14 + px
    int pw = k & 15, ph = (k >> 4) & 15, cin = k >> 8;
    int px = m % 14, py = (m / 14) % 14, b = m / NPATCH;
    int row = py * 16 + ph, col = px * 16 + pw;
    Xp[i] = x[((size_t)(b * 3 + cin) * 224 + row) * 224 + col];
}

// ---------------- h init: cls + patches + pos ----------------
__global__ void build_h(const float* __restrict__ pe, const float* __restrict__ patch_b,
                        const float* __restrict__ cls, const float* __restrict__ pos,
                        float* __restrict__ h) {
    int i = blockIdx.x * 256 + threadIdx.x;
    if (i >= MT * DD) return;
    int d = i % DD;
    int s = (i / DD) % SS;
    int b = i / (DD * SS);
    float v;
    if (s == 0) v = cls[d];
    else        v = pe[((size_t)(b * NPATCH) + (s - 1)) * DD + d] + patch_b[d];
    h[i] = v + pos[s * DD + d];
}

// ---------------- generic fp32 GEMM, C[M,N] = A[M,K] @ W[N,K]^T (+bias) (+accum) ----------------
// mode 0: store; mode 1: store + bias; mode 2: accumulate into C + bias
__global__ __launch_bounds__(256) void gemm_nt_kernel(
    const float* __restrict__ A, const float* __restrict__ W,
    const float* __restrict__ bias, float* __restrict__ C,
    int M, int N, int K, int mode)
{
    __shared__ float As[16][65];
    __shared__ float Ws[16][65];
    int tid = threadIdx.x;
    int n0 = blockIdx.x * 64;
    int m0 = blockIdx.y * 64;
    int ty = tid >> 4, tx = tid & 15;
    float acc[4][4] = {};
    int lr = tid >> 2;          // 0..63
    int lk = (tid & 3) << 2;    // 0,4,8,12
    int arow = m0 + lr; if (arow >= M) arow = M - 1;
    const float* Aptr = A + (size_t)arow * K + lk;
    const float* Wptr = W + (size_t)(n0 + lr) * K + lk;
    for (int k0 = 0; k0 < K; k0 += 16) {
        float4 av = *(const float4*)(Aptr + k0);
        float4 wv = *(const float4*)(Wptr + k0);
        __syncthreads();
        As[lk+0][lr] = av.x; As[lk+1][lr] = av.y; As[lk+2][lr] = av.z; As[lk+3][lr] = av.w;
        Ws[lk+0][lr] = wv.x; Ws[lk+1][lr] = wv.y; Ws[lk+2][lr] = wv.z; Ws[lk+3][lr] = wv.w;
        __syncthreads();
        #pragma unroll
        for (int kk = 0; kk < 16; kk++) {
            float a[4], w[4];
            #pragma unroll
            for (int i = 0; i < 4; i++) a[i] = As[kk][ty*4+i];
            #pragma unroll
            for (int j = 0; j < 4; j++) w[j] = Ws[kk][tx*4+j];
            #pragma unroll
            for (int i = 0; i < 4; i++)
                #pragma unroll
                for (int j = 0; j < 4; j++)
                    acc[i][j] += a[i] * w[j];
        }
    }
    #pragma unroll
    for (int i = 0; i < 4; i++) {
        int row = m0 + ty*4 + i;
        if (row >= M) continue;
        #pragma unroll
        for (int j = 0; j < 4; j++) {
            int col = n0 + tx*4 + j;
            float v = acc[i][j];
            if (mode >= 1) v += bias[col];
            float* p = C + (size_t)row * N + col;
            if (mode == 2) v += *p;
            *p = v;
        }
    }
}

// ---------------- LayerNorm over D=768 per token ----------------
__global__ __launch_bounds__(256) void ln_kernel(const float* __restrict__ x,
                                                 const float* __restrict__ g,
                                                 const float* __restrict__ b,
                                                 float* __restrict__ y)
{
    int m = blockIdx.x, t = threadIdx.x;
    __shared__ float buf[DD];
    __shared__ float tmp[4];
    float s = 0.f;
    for (int j = t; j < DD; j += 256) { float v = x[(size_t)m*DD + j]; buf[j] = v; s += v; }
    #pragma unroll
    for (int o = 32; o > 0; o >>= 1) s += __shfl_down(s, o);
    if ((t & 63) == 0) tmp[t >> 6] = s;
    __syncthreads();
    float mean = (tmp[0]+tmp[1]+tmp[2]+tmp[3]) * (1.0f/DD);
    float s2 = 0.f;
    for (int j = t; j < DD; j += 256) { float d = buf[j] - mean; s2 += d*d; }
    #pragma unroll
    for (int o = 32; o > 0; o >>= 1) s2 += __shfl_down(s2, o);
    __syncthreads();
    if ((t & 63) == 0) tmp[t >> 6] = s2;
    __syncthreads();
    float var = (tmp[0]+tmp[1]+tmp[2]+tmp[3]) * (1.0f/DD);
    float rs = rsqrtf(var + 1e-5f);
    for (int j = t; j < DD; j += 256)
        y[(size_t)m*DD + j] = (buf[j] - mean) * rs * g[j] + b[j];
}

// ---------------- fused attention: one block per (qi, head, b) ----------------
__global__ __launch_bounds__(256) void attn_kernel(const float* __restrict__ q,
                                                   const float* __restrict__ kv,
                                                   float* __restrict__ o)
{
    int qi = blockIdx.x, hh = blockIdx.y, b = blockIdx.z;
    int t = threadIdx.x;
    __shared__ float qs[64];
    __shared__ float sc[SS];
    __shared__ float tmp[4];
    __shared__ float ob[4][64];
    if (t < 64) qs[t] = q[((size_t)(b*SS + qi))*DD + hh*64 + t];
    __syncthreads();
    float sv = -1e30f;
    if (t < SS) {
        const float* kr = kv + ((size_t)(b*SS + t))*1536 + hh*64;
        float s = 0.f;
        #pragma unroll
        for (int d = 0; d < 64; d++) s += qs[d] * kr[d];
        s *= 0.125f;
        sc[t] = s;
        sv = s;
    }
    float mx = sv;
    #pragma unroll
    for (int off = 32; off > 0; off >>= 1) mx = fmaxf(mx, __shfl_down(mx, off));
    if ((t & 63) == 0) tmp[t >> 6] = mx;
    __syncthreads();
    mx = fmaxf(fmaxf(tmp[0], tmp[1]), fmaxf(tmp[2], tmp[3]));
    float es = 0.f;
    if (t < SS) { float e = expf(sc[t] - mx); sc[t] = e; es = e; }
    #pragma unroll
    for (int off = 32; off > 0; off >>= 1) es += __shfl_down(es, off);
    __syncthreads();
    if ((t & 63) == 0) tmp[t >> 6] = es;
    __syncthreads();
    float Z = tmp[0]+tmp[1]+tmp[2]+tmp[3];
    float inv = 1.0f / Z;
    int d = t & 63, c = t >> 6;
    float acc = 0.f;
    for (int ki = c; ki < SS; ki += 4)
        acc += sc[ki] * kv[((size_t)(b*SS + ki))*1536 + 768 + hh*64 + d];
    ob[c][d] = acc;
    __syncthreads();
    if (t < 64) {
        float r = (ob[0][t]+ob[1][t]+ob[2][t]+ob[3][t]) * inv;
        o[((size_t)(b*SS + qi))*DD + hh*64 + t] = r;
    }
}

// ---------------- zero expert counters ----------------
__global__ void zero_cnt(int* cnt) { if (threadIdx.x < NEXP) cnt[threadIdx.x] = 0; }

// ---------------- gate: logits -> top1 + gv, compaction ----------------
__global__ __launch_bounds__(256) void gate_kernel(const float* __restrict__ y,
                                                   const float* __restrict__ gw,
                                                   const float* __restrict__ gb,
                                                   float* __restrict__ gv,
                                                   int* __restrict__ cnt,
                                                   int* __restrict__ idx)
{
    int m = blockIdx.x, t = threadIdx.x;
    const float* yr = y + (size_t)m * DD;
    float p[NEXP] = {0,0,0,0};
    for (int k = t; k < DD; k += 256) {
        float v = yr[k];
        p[0] += v * gw[k];
        p[1] += v * gw[DD + k];
        p[2] += v * gw[2*DD + k];
        p[3] += v * gw[3*DD + k];
    }
    __shared__ float tmp[4];
    float l[NEXP];
    #pragma unroll
    for (int e = 0; e < NEXP; e++) {
        float s = p[e];
        #pragma unroll
        for (int off = 32; off > 0; off >>= 1) s += __shfl_down(s, off);
        __syncthreads();
        if ((t & 63) == 0) tmp[t >> 6] = s;
        __syncthreads();
        l[e] = tmp[0]+tmp[1]+tmp[2]+tmp[3] + gb[e];
    }
    if (t == 0) {
        int top = 0; float best = l[0];
        #pragma unroll
        for (int e = 1; e < NEXP; e++) if (l[e] > best) { best = l[e]; top = e; }
        float Z = 0.f;
        #pragma unroll
        for (int e = 0; e < NEXP; e++) Z += expf(l[e] - best);
        gv[m] = 1.0f / Z;   // probs[argmax] = exp(0)/Z
        int pos = atomicAdd(&cnt[top], 1);
        idx[top * MT + pos] = m;
    }
}

// ---------------- MoE GEMM1 (gathered rows): hidd = gelu(y @ w1[e] + b1[e]) ----------------
__global__ __launch_bounds__(256) void moe_gemm1_kernel(
    const float* __restrict__ Y, const float* __restrict__ W1,
    const float* __restrict__ B1, const int* __restrict__ cnt,
    const int* __restrict__ idx, float* __restrict__ Hd)
{
    int e = blockIdx.z;
    int count = cnt[e];
    int m0 = blockIdx.y * 64;
    if (m0 >= count) return;
    int n0 = blockIdx.x * 64;
    const float* W  = W1 + (size_t)e * DD * HHID;
    const float* Be = B1 + e * HHID;
    __shared__ float As[16][65];
    __shared__ float Ws[16][65];
    __shared__ int toks[64];
    int tid = threadIdx.x;
    if (tid < 64) {
        int mm = m0 + tid;
        toks[tid] = (mm < count) ? idx[e * MT + mm] : -1;
    }
    __syncthreads();
    int ty = tid >> 4, tx = tid & 15;
    float acc[4][4] = {};
    int lr = tid >> 2, lk = (tid & 3) << 2;
    int tok = toks[lr]; int atok = tok < 0 ? 0 : tok;
    const float* Aptr = Y + (size_t)atok * DD + lk;
    int wc = (tid & 15) << 2, wk = tid >> 4;
    for (int k0 = 0; k0 < DD; k0 += 16) {
        float4 av = *(const float4*)(Aptr + k0);
        float4 wv = *(const float4*)(W + (size_t)(k0 + wk) * HHID + n0 + wc);
        __syncthreads();
        As[lk+0][lr] = av.x; As[lk+1][lr] = av.y; As[lk+2][lr] = av.z; As[lk+3][lr] = av.w;
        Ws[wk][wc+0] = wv.x; Ws[wk][wc+1] = wv.y; Ws[wk][wc+2] = wv.z; Ws[wk][wc+3] = wv.w;
        __syncthreads();
        #pragma unroll
        for (int kk = 0; kk < 16; kk++) {
            float a[4], w[4];
            #pragma unroll
            for (int i = 0; i < 4; i++) a[i] = As[kk][ty*4+i];
            #pragma unroll
            for (int j = 0; j < 4; j++) w[j] = Ws[kk][tx*4+j];
            #pragma unroll
            for (int i = 0; i < 4; i++)
                #pragma unroll
                for (int j = 0; j < 4; j++)
                    acc[i][j] += a[i] * w[j];
        }
    }
    #pragma unroll
    for (int i = 0; i < 4; i++) {
        int rr = ty*4 + i;
        int tk = toks[rr];
        if (tk < 0) continue;
        #pragma unroll
        for (int j = 0; j < 4; j++) {
            int col = n0 + tx*4 + j;
            float v = acc[i][j] + Be[col];
            float g = 0.5f * v * (1.0f + tanhf(0.7978845608028654f * (v + 0.044715f * v * v * v)));
            Hd[(size_t)tk * HHID + col] = g;
        }
    }
}

// ---------------- MoE GEMM2 (gathered rows): h += (hidd @ w2[e] + b2[e]) * gv ----------------
__global__ __launch_bounds__(256) void moe_gemm2_kernel(
    const float* __restrict__ Hd, const float* __restrict__ W2,
    const float* __restrict__ B2, const int* __restrict__ cnt,
    const int* __restrict__ idx, const float* __restrict__ gv,
    float* __restrict__ h)
{
    int e = blockIdx.z;
    int count = cnt[e];
    int m0 = blockIdx.y * 64;
    if (m0 >= count) return;
    int n0 = blockIdx.x * 64;
    const float* W  = W2 + (size_t)e * HHID * DD;
    const float* Be = B2 + e * DD;
    __shared__ float As[16][65];
    __shared__ float Ws[16][65];
    __shared__ int toks[64];
    __shared__ float gvs[64];
    int tid = threadIdx.x;
    if (tid < 64) {
        int mm = m0 + tid;
        int tk = (mm < count) ? idx[e * MT + mm] : -1;
        toks[tid] = tk;
        gvs[tid] = (tk >= 0) ? gv[tk] : 0.f;
    }
    __syncthreads();
    int ty = tid >> 4, tx = tid & 15;
    float acc[4][4] = {};
    int lr = tid >> 2, lk = (tid & 3) << 2;
    int tok = toks[lr]; int atok = tok < 0 ? 0 : tok;
    const float* Aptr = Hd + (size_t)atok * HHID + lk;
    int wc = (tid & 15) << 2, wk = tid >> 4;
    for (int k0 = 0; k0 < HHID; k0 += 16) {
        float4 av = *(const float4*)(Aptr + k0);
        float4 wv = *(const float4*)(W + (size_t)(k0 + wk) * DD + n0 + wc);
        __syncthreads();
        As[lk+0][lr] = av.x; As[lk+1][lr] = av.y; As[lk+2][lr] = av.z; As[lk+3][lr] = av.w;
        Ws[wk][wc+0] = wv.x; Ws[wk][wc+1] = wv.y; Ws[wk][wc+2] = wv.z; Ws[wk][wc+3] = wv.w;
        __syncthreads();
        #pragma unroll
        for (int kk = 0; kk < 16; kk++) {
            float a[4], w[4];
            #pragma unroll
            for (int i = 0; i < 4; i++) a[i] = As[kk][ty*4+i];
            #pragma unroll
            for (int j = 0; j < 4; j++) w[j] = Ws[kk][tx*4+j];
            #pragma unroll
            for (int i = 0; i < 4; i++)
                #pragma unroll
                for (int j = 0; j < 4; j++)
                    acc[i][j] += a[i] * w[j];
        }
    }
    #pragma unroll
    for (int i = 0; i < 4; i++) {
        int rr = ty*4 + i;
        int tk = toks[rr];
        if (tk < 0) continue;
        float g = gvs[rr];
        #pragma unroll
        for (int j = 0; j < 4; j++) {
            int col = n0 + tx*4 + j;
            h[(size_t)tk * DD + col] += (acc[i][j] + Be[col]) * g;
        }
    }
}

// ---------------- classifier head ----------------
__global__ void head_kernel(const float* __restrict__ h, const float* __restrict__ hw,
                            const float* __restrict__ hb, float* __restrict__ out)
{
    int i = blockIdx.x * 256 + threadIdx.x;
    if (i >= BB * 1000) return;
    int b = i & 7, n = i >> 3;
    const float* hr = h + (size_t)(b * SS) * DD;   // h[b, 0, :]
    const float* wr = hw + (size_t)n * DD;
    float s = 0.f;
    for (int k = 0; k < DD; k++) s += hr[k] * wr[k];
    out[b * 1000 + n] = s + hb[n];
}

extern "C" void kernel_launch(void* const* d_in, const int* in_sizes, int n_in,
                              void* d_out, int out_size, void* d_ws, size_t ws_size,
                              hipStream_t stream) {
    const float* x          = (const float*)d_in[0];
    const float* patch_w    = (const float*)d_in[1];
    const float* patch_b    = (const float*)d_in[2];
    const float* cls_token  = (const float*)d_in[3];
    const float* pos_embed  = (const float*)d_in[4];
    const float* ln1_g      = (const float*)d_in[5];
    const float* ln1_b      = (const float*)d_in[6];
    const float* ln2_g      = (const float*)d_in[7];
    const float* ln2_b      = (const float*)d_in[8];
    const float* attn_in_w  = (const float*)d_in[9];
    const float* attn_in_b  = (const float*)d_in[10];
    const float* attn_out_w = (const float*)d_in[11];
    const float* attn_out_b = (const float*)d_in[12];
    const float* gate_w     = (const float*)d_in[13];
    const float* gate_b     = (const float*)d_in[14];
    const float* w1         = (const float*)d_in[15];
    const float* b1         = (const float*)d_in[16];
    const float* w2         = (const float*)d_in[17];
    const float* b2         = (const float*)d_in[18];
    const float* head_w     = (const float*)d_in[19];
    const float* head_b     = (const float*)d_in[20];
    float* out = (float*)d_out;

    float* ws = (float*)d_ws;
    float* Xp  = ws;                    // 1568*768 = 1204224
    float* pe  = Xp  + 1204224;         // 1204224
    float* h   = pe  + 1204224;         // 1576*768 = 1210368
    float* qn  = h   + 1210368;
    float* qb  = qn  + 1210368;
    float* kvb = qb  + 1210368;         // 1576*1536 = 2420736
    float* ob  = kvb + 2420736;
    float* yb  = ob  + 1210368;
    float* hd  = yb  + 1210368;         // 1576*3072 = 4841472
    float* gv  = hd  + 4841472;         // 1576 (pad to 1600)
    int*   cnt  = (int*)(gv + 1600);
    int*   idxb = cnt + 64;             // 4*1576

    dim3 blk(256);

    gather_patches<<<(MPE*DD + 255)/256, blk, 0, stream>>>(x, Xp);
    gemm_nt_kernel<<<dim3(DD/64, (MPE+63)/64), blk, 0, stream>>>(Xp, patch_w, nullptr, pe, MPE, DD, DD, 0);
    build_h<<<(MT*DD + 255)/256, blk, 0, stream>>>(pe, patch_b, cls_token, pos_embed, h);

    for (int i = 0; i < 12; i++) {
        const float* aw  = attn_in_w  + (size_t)i * 2304 * DD;
        const float* ab  = attn_in_b  + (size_t)i * 2304;
        const float* ow  = attn_out_w + (size_t)i * DD * DD;
        const float* obias = attn_out_b + (size_t)i * DD;
        const float* l1g = ln1_g + (size_t)i * DD;
        const float* l1b = ln1_b + (size_t)i * DD;
        const float* l2g = ln2_g + (size_t)i * DD;
        const float* l2b = ln2_b + (size_t)i * DD;
        const float* gw  = gate_w + (size_t)i * NEXP * DD;
        const float* gb  = gate_b + (size_t)i * NEXP;
        const float* w1l = w1 + (size_t)i * NEXP * DD * HHID;
        const float* b1l = b1 + (size_t)i * NEXP * HHID;
        const float* w2l = w2 + (size_t)i * NEXP * HHID * DD;
        const float* b2l = b2 + (size_t)i * NEXP * DD;

        ln_kernel<<<MT, blk, 0, stream>>>(h, l1g, l1b, qn);
        gemm_nt_kernel<<<dim3(12, 25), blk, 0, stream>>>(qn, aw, ab, qb, MT, DD, DD, 1);
        gemm_nt_kernel<<<dim3(24, 25), blk, 0, stream>>>(h, aw + DD*DD, ab + DD, kvb, MT, 1536, DD, 1);
        attn_kernel<<<dim3(SS, 12, BB), blk, 0, stream>>>(qb, kvb, ob);
        gemm_nt_kernel<<<dim3(12, 25), blk, 0, stream>>>(ob, ow, obias, h, MT, DD, DD, 2);
        ln_kernel<<<MT, blk, 0, stream>>>(h, l2g, l2b, yb);
        zero_cnt<<<1, 64, 0, stream>>>(cnt);
        gate_kernel<<<MT, blk, 0, stream>>>(yb, gw, gb, gv, cnt, idxb);
        moe_gemm1_kernel<<<dim3(HHID/64, 25, NEXP), blk, 0, stream>>>(yb, w1l, b1l, cnt, idxb, hd);
        moe_gemm2_kernel<<<dim3(DD/64, 25, NEXP), blk, 0, stream>>>(hd, w2l, b2l, cnt, idxb, gv, h);
    }

    head_kernel<<<(BB*1000 + 255)/256, blk, 0, stream>>>(h, head_w, head_b, out);
}

// Round 2
// 5164.038 us; speedup vs baseline: 2.4126x; 2.4126x over previous
//
#include <hip/hip_runtime.h>
#include <math.h>

// MoE ViT forward. bf16-MFMA GEMMs, fp32 everything else.
// B=8, S=197, D=768, NH=12, HD=64, E=4, HID=3072, DEPTH=12, NC=1000

#define BB 8
#define SS 197
#define DD 768
#define MT (BB*SS)      // 1576 tokens
#define NPATCH 196
#define MPE (BB*NPATCH) // 1568
#define HHID 3072
#define NEXP 4

typedef __bf16 bf16_t;
typedef bf16_t bf16x8 __attribute__((ext_vector_type(8)));
typedef float  f32x4  __attribute__((ext_vector_type(4)));

// ---------------- patch gather: Xp[m,k] = x[b,cin, py*16+ph, px*16+pw] ----------------
__global__ void gather_patches(const float* __restrict__ x, float* __restrict__ Xp) {
    int i = blockIdx.x * 256 + threadIdx.x;
    if (i >= MPE * DD) return;
    int k = i % DD;       // cin*256 + ph*16 + pw
    int m = i / DD;       // b*196 + py*14 + px
    int pw = k & 15, ph = (k >> 4) & 15, cin = k >> 8;
    int px = m % 14, py = (m / 14) % 14, b = m / NPATCH;
    int row = py * 16 + ph, col = px * 16 + pw;
    Xp[i] = x[((size_t)(b * 3 + cin) * 224 + row) * 224 + col];
}

// ---------------- h init: cls + patches + pos ----------------
__global__ void build_h(const float* __restrict__ pe, const float* __restrict__ patch_b,
                        const float* __restrict__ cls, const float* __restrict__ pos,
                        float* __restrict__ h) {
    int i = blockIdx.x * 256 + threadIdx.x;
    if (i >= MT * DD) return;
    int d = i % DD;
    int s = (i / DD) % SS;
    int b = i / (DD * SS);
    float v;
    if (s == 0) v = cls[d];
    else        v = pe[((size_t)(b * NPATCH) + (s - 1)) * DD + d] + patch_b[d];
    h[i] = v + pos[s * DD + d];
}

// ---------------- fp32 -> bf16 straight convert ----------------
__global__ void cvt_bf16(const float* __restrict__ in, bf16_t* __restrict__ out, int n) {
    int i = (blockIdx.x * 256 + threadIdx.x) * 8;
    if (i >= n) return;
    const float4* p = (const float4*)(in + i);
    float4 a = p[0], b = p[1];
    bf16x8 o;
    o[0]=(bf16_t)a.x; o[1]=(bf16_t)a.y; o[2]=(bf16_t)a.z; o[3]=(bf16_t)a.w;
    o[4]=(bf16_t)b.x; o[5]=(bf16_t)b.y; o[6]=(bf16_t)b.z; o[7]=(bf16_t)b.w;
    *(bf16x8*)(out + i) = o;
}

// ---------------- fp32 [R][C] -> bf16 [C][R] transpose-convert (per blockIdx.z slab) ----------------
__global__ __launch_bounds__(256) void transpose_cvt(const float* __restrict__ in,
                                                     bf16_t* __restrict__ out, int R, int C) {
    int z = blockIdx.z;
    in  += (size_t)z * R * C;
    out += (size_t)z * R * C;
    __shared__ float t[32][33];
    int c0 = blockIdx.x * 32, r0 = blockIdx.y * 32;
    int tx = threadIdx.x & 31, ty = threadIdx.x >> 5;  // 32x8
    #pragma unroll
    for (int i = 0; i < 4; i++)
        t[ty + 8*i][tx] = in[(size_t)(r0 + ty + 8*i) * C + c0 + tx];
    __syncthreads();
    #pragma unroll
    for (int i = 0; i < 4; i++)
        out[(size_t)(c0 + ty + 8*i) * R + r0 + tx] = (bf16_t)t[tx][ty + 8*i];
}

// ---------------- unified bf16-MFMA GEMM ----------------
// C[M,N] = A[M,K] (fp32, cvt inline) @ B[N,K]^T (bf16)
// MODE 0: store; 1: store+bias; 2: C += v+bias; 3: gather + gelu(v+bias) store; 4: gather + C += (v+bias)*gv
template<int MODE>
__global__ __launch_bounds__(256) void gemm_bf16(
    const float* __restrict__ A, const bf16_t* __restrict__ Bw,
    const float* __restrict__ bias, float* __restrict__ C,
    const int* __restrict__ cnt, const int* __restrict__ idx,
    const float* __restrict__ gv, int M, int N, int K)
{
    constexpr bool GATHER = (MODE >= 3);
    int z = blockIdx.z;
    int count = GATHER ? cnt[z] : M;
    int m0 = blockIdx.y * 64;
    if (m0 >= count) return;
    int n0 = blockIdx.x * 64;
    Bw += (size_t)z * N * K;
    const float* biasz = bias ? (bias + (size_t)z * N) : nullptr;

    __shared__ bf16_t As[64 * 32];
    __shared__ bf16_t Bs[64 * 32];
    __shared__ int toks[64];

    int tid = threadIdx.x;
    if (tid < 64) {
        int mm = m0 + tid;
        if (mm > count - 1) mm = count - 1;
        toks[tid] = GATHER ? idx[z * MT + mm] : mm;
    }
    __syncthreads();

    // staging: thread -> (row sr, k-slot ss of 8)
    int sr = tid >> 2;
    int ss = tid & 3;
    int sswz = ss ^ ((sr >> 1) & 3);
    const float*  Ap = A  + (size_t)toks[sr] * K + ss * 8;
    const bf16_t* Bp = Bw + (size_t)(n0 + sr) * K + ss * 8;

    int lane = tid & 63, w = tid >> 6;
    int wm = (w >> 1) * 32, wn = (w & 1) * 32;   // wave's 32x32 quadrant
    int fr = lane & 15, fs = lane >> 4;

    f32x4 acc[2][2];
    #pragma unroll
    for (int mi = 0; mi < 2; mi++)
        #pragma unroll
        for (int ni = 0; ni < 2; ni++)
            #pragma unroll
            for (int j = 0; j < 4; j++) acc[mi][ni][j] = 0.f;

    float4 au = *(const float4*)(Ap);
    float4 av = *(const float4*)(Ap + 4);
    bf16x8 bv = *(const bf16x8*)(Bp);

    for (int k0 = 0; k0 < K; k0 += 32) {
        bf16x8 apk;
        apk[0]=(bf16_t)au.x; apk[1]=(bf16_t)au.y; apk[2]=(bf16_t)au.z; apk[3]=(bf16_t)au.w;
        apk[4]=(bf16_t)av.x; apk[5]=(bf16_t)av.y; apk[6]=(bf16_t)av.z; apk[7]=(bf16_t)av.w;
        *(bf16x8*)&As[sr * 32 + sswz * 8] = apk;
        *(bf16x8*)&Bs[sr * 32 + sswz * 8] = bv;
        __syncthreads();
        if (k0 + 32 < K) {
            au = *(const float4*)(Ap + k0 + 32);
            av = *(const float4*)(Ap + k0 + 36);
            bv = *(const bf16x8*)(Bp + k0 + 32);
        }
        bf16x8 afrag[2], bfrag[2];
        #pragma unroll
        for (int mi = 0; mi < 2; mi++) {
            int r = wm + mi * 16 + fr;
            afrag[mi] = *(bf16x8*)&As[r * 32 + (fs ^ ((r >> 1) & 3)) * 8];
        }
        #pragma unroll
        for (int ni = 0; ni < 2; ni++) {
            int r = wn + ni * 16 + fr;
            bfrag[ni] = *(bf16x8*)&Bs[r * 32 + (fs ^ ((r >> 1) & 3)) * 8];
        }
        #pragma unroll
        for (int mi = 0; mi < 2; mi++)
            #pragma unroll
            for (int ni = 0; ni < 2; ni++)
                acc[mi][ni] = __builtin_amdgcn_mfma_f32_16x16x32_bf16(afrag[mi], bfrag[ni], acc[mi][ni], 0, 0, 0);
        __syncthreads();
    }

    // epilogue: C/D layout col=lane&15, row=(lane>>4)*4+j
    #pragma unroll
    for (int mi = 0; mi < 2; mi++) {
        #pragma unroll
        for (int j = 0; j < 4; j++) {
            int rr = wm + mi * 16 + fs * 4 + j;
            if (m0 + rr >= count) continue;
            int crow = toks[rr];
            #pragma unroll
            for (int ni = 0; ni < 2; ni++) {
                int col = n0 + wn + ni * 16 + fr;
                float v = acc[mi][ni][j];
                if (MODE >= 1) v += biasz[col];
                float* p = C + (size_t)crow * N + col;
                if (MODE == 0 || MODE == 1) *p = v;
                else if (MODE == 2) *p += v;
                else if (MODE == 3) {
                    float g = 0.5f * v * (1.0f + tanhf(0.7978845608028654f * (v + 0.044715f * v * v * v)));
                    *p = g;
                } else {
                    *p += v * gv[crow];
                }
            }
        }
    }
}

// ---------------- LayerNorm over D=768 per token ----------------
__global__ __launch_bounds__(256) void ln_kernel(const float* __restrict__ x,
                                                 const float* __restrict__ g,
                                                 const float* __restrict__ b,
                                                 float* __restrict__ y)
{
    int m = blockIdx.x, t = threadIdx.x;
    __shared__ float buf[DD];
    __shared__ float tmp[4];
    float s = 0.f;
    for (int j = t; j < DD; j += 256) { float v = x[(size_t)m*DD + j]; buf[j] = v; s += v; }
    #pragma unroll
    for (int o = 32; o > 0; o >>= 1) s += __shfl_down(s, o);
    if ((t & 63) == 0) tmp[t >> 6] = s;
    __syncthreads();
    float mean = (tmp[0]+tmp[1]+tmp[2]+tmp[3]) * (1.0f/DD);
    float s2 = 0.f;
    for (int j = t; j < DD; j += 256) { float d = buf[j] - mean; s2 += d*d; }
    #pragma unroll
    for (int o = 32; o > 0; o >>= 1) s2 += __shfl_down(s2, o);
    __syncthreads();
    if ((t & 63) == 0) tmp[t >> 6] = s2;
    __syncthreads();
    float var = (tmp[0]+tmp[1]+tmp[2]+tmp[3]) * (1.0f/DD);
    float rs = rsqrtf(var + 1e-5f);
    for (int j = t; j < DD; j += 256)
        y[(size_t)m*DD + j] = (buf[j] - mean) * rs * g[j] + b[j];
}

// ---------------- fused attention: one block per (qi, head, b) ----------------
__global__ __launch_bounds__(256) void attn_kernel(const float* __restrict__ q,
                                                   const float* __restrict__ kv,
                                                   float* __restrict__ o)
{
    int qi = blockIdx.x, hh = blockIdx.y, b = blockIdx.z;
    int t = threadIdx.x;
    __shared__ float qs[64];
    __shared__ float sc[SS];
    __shared__ float tmp[4];
    __shared__ float ob[4][64];
    if (t < 64) qs[t] = q[((size_t)(b*SS + qi))*DD + hh*64 + t];
    __syncthreads();
    float sv = -1e30f;
    if (t < SS) {
        const float* kr = kv + ((size_t)(b*SS + t))*1536 + hh*64;
        float s = 0.f;
        #pragma unroll
        for (int d = 0; d < 64; d++) s += qs[d] * kr[d];
        s *= 0.125f;
        sc[t] = s;
        sv = s;
    }
    float mx = sv;
    #pragma unroll
    for (int off = 32; off > 0; off >>= 1) mx = fmaxf(mx, __shfl_down(mx, off));
    if ((t & 63) == 0) tmp[t >> 6] = mx;
    __syncthreads();
    mx = fmaxf(fmaxf(tmp[0], tmp[1]), fmaxf(tmp[2], tmp[3]));
    float es = 0.f;
    if (t < SS) { float e = expf(sc[t] - mx); sc[t] = e; es = e; }
    #pragma unroll
    for (int off = 32; off > 0; off >>= 1) es += __shfl_down(es, off);
    __syncthreads();
    if ((t & 63) == 0) tmp[t >> 6] = es;
    __syncthreads();
    float Z = tmp[0]+tmp[1]+tmp[2]+tmp[3];
    float inv = 1.0f / Z;
    int d = t & 63, c = t >> 6;
    float acc = 0.f;
    for (int ki = c; ki < SS; ki += 4)
        acc += sc[ki] * kv[((size_t)(b*SS + ki))*1536 + 768 + hh*64 + d];
    ob[c][d] = acc;
    __syncthreads();
    if (t < 64) {
        float r = (ob[0][t]+ob[1][t]+ob[2][t]+ob[3][t]) * inv;
        o[((size_t)(b*SS + qi))*DD + hh*64 + t] = r;
    }
}

// ---------------- zero expert counters ----------------
__global__ void zero_cnt(int* cnt) { if (threadIdx.x < NEXP) cnt[threadIdx.x] = 0; }

// ---------------- gate: logits -> top1 + gv, compaction ----------------
__global__ __launch_bounds__(256) void gate_kernel(const float* __restrict__ y,
                                                   const float* __restrict__ gw,
                                                   const float* __restrict__ gb,
                                                   float* __restrict__ gv,
                                                   int* __restrict__ cnt,
                                                   int* __restrict__ idx)
{
    int m = blockIdx.x, t = threadIdx.x;
    const float* yr = y + (size_t)m * DD;
    float p[NEXP] = {0,0,0,0};
    for (int k = t; k < DD; k += 256) {
        float v = yr[k];
        p[0] += v * gw[k];
        p[1] += v * gw[DD + k];
        p[2] += v * gw[2*DD + k];
        p[3] += v * gw[3*DD + k];
    }
    __shared__ float tmp[4];
    float l[NEXP];
    #pragma unroll
    for (int e = 0; e < NEXP; e++) {
        float s = p[e];
        #pragma unroll
        for (int off = 32; off > 0; off >>= 1) s += __shfl_down(s, off);
        __syncthreads();
        if ((t & 63) == 0) tmp[t >> 6] = s;
        __syncthreads();
        l[e] = tmp[0]+tmp[1]+tmp[2]+tmp[3] + gb[e];
    }
    if (t == 0) {
        int top = 0; float best = l[0];
        #pragma unroll
        for (int e = 1; e < NEXP; e++) if (l[e] > best) { best = l[e]; top = e; }
        float Z = 0.f;
        #pragma unroll
        for (int e = 0; e < NEXP; e++) Z += expf(l[e] - best);
        gv[m] = 1.0f / Z;   // probs[argmax]
        int pos = atomicAdd(&cnt[top], 1);
        idx[top * MT + pos] = m;
    }
}

// ---------------- classifier head ----------------
__global__ void head_kernel(const float* __restrict__ h, const float* __restrict__ hw,
                            const float* __restrict__ hb, float* __restrict__ out)
{
    int i = blockIdx.x * 256 + threadIdx.x;
    if (i >= BB * 1000) return;
    int b = i & 7, n = i >> 3;
    const float* hr = h + (size_t)(b * SS) * DD;   // h[b, 0, :]
    const float* wr = hw + (size_t)n * DD;
    float s = 0.f;
    for (int k = 0; k < DD; k++) s += hr[k] * wr[k];
    out[b * 1000 + n] = s + hb[n];
}

extern "C" void kernel_launch(void* const* d_in, const int* in_sizes, int n_in,
                              void* d_out, int out_size, void* d_ws, size_t ws_size,
                              hipStream_t stream) {
    const float* x          = (const float*)d_in[0];
    const float* patch_w    = (const float*)d_in[1];
    const float* patch_b    = (const float*)d_in[2];
    const float* cls_token  = (const float*)d_in[3];
    const float* pos_embed  = (const float*)d_in[4];
    const float* ln1_g      = (const float*)d_in[5];
    const float* ln1_b      = (const float*)d_in[6];
    const float* ln2_g      = (const float*)d_in[7];
    const float* ln2_b      = (const float*)d_in[8];
    const float* attn_in_w  = (const float*)d_in[9];
    const float* attn_in_b  = (const float*)d_in[10];
    const float* attn_out_w = (const float*)d_in[11];
    const float* attn_out_b = (const float*)d_in[12];
    const float* gate_w     = (const float*)d_in[13];
    const float* gate_b     = (const float*)d_in[14];
    const float* w1         = (const float*)d_in[15];
    const float* b1         = (const float*)d_in[16];
    const float* w2         = (const float*)d_in[17];
    const float* b2         = (const float*)d_in[18];
    const float* head_w     = (const float*)d_in[19];
    const float* head_b     = (const float*)d_in[20];
    float* out = (float*)d_out;

    char* wsb = (char*)d_ws;
    auto alloc = [&](size_t bytes) { char* p = wsb; wsb += (bytes + 63) & ~63ULL; return p; };
    float* Xp  = (float*)alloc((size_t)MPE * DD * 4);
    float* pe  = (float*)alloc((size_t)MPE * DD * 4);
    float* h   = (float*)alloc((size_t)MT * DD * 4);
    float* qn  = (float*)alloc((size_t)MT * DD * 4);
    float* qb  = (float*)alloc((size_t)MT * DD * 4);
    float* kvb = (float*)alloc((size_t)MT * 1536 * 4);
    float* ob  = (float*)alloc((size_t)MT * DD * 4);
    float* yb  = (float*)alloc((size_t)MT * DD * 4);
    float* hd  = (float*)alloc((size_t)MT * HHID * 4);
    float* gv  = (float*)alloc((size_t)MT * 4);
    int*   cnt  = (int*)alloc(64 * 4);
    int*   idxb = (int*)alloc((size_t)NEXP * MT * 4);
    bf16_t* wq_bf = (bf16_t*)alloc((size_t)2304 * DD * 2);
    bf16_t* wo_bf = (bf16_t*)alloc((size_t)DD * DD * 2);
    bf16_t* w1t   = (bf16_t*)alloc((size_t)NEXP * DD * HHID * 2);
    bf16_t* w2t   = (bf16_t*)alloc((size_t)NEXP * DD * HHID * 2);
    bf16_t* pw_bf = (bf16_t*)alloc((size_t)DD * DD * 2);

    dim3 blk(256);

    cvt_bf16<<<(DD*DD/8 + 255)/256, blk, 0, stream>>>(patch_w, pw_bf, DD*DD);
    gather_patches<<<(MPE*DD + 255)/256, blk, 0, stream>>>(x, Xp);
    gemm_bf16<0><<<dim3(DD/64, (MPE+63)/64, 1), blk, 0, stream>>>(
        Xp, pw_bf, nullptr, pe, nullptr, nullptr, nullptr, MPE, DD, DD);
    build_h<<<(MT*DD + 255)/256, blk, 0, stream>>>(pe, patch_b, cls_token, pos_embed, h);

    for (int i = 0; i < 12; i++) {
        const float* aw    = attn_in_w  + (size_t)i * 2304 * DD;
        const float* ab    = attn_in_b  + (size_t)i * 2304;
        const float* ow    = attn_out_w + (size_t)i * DD * DD;
        const float* obias = attn_out_b + (size_t)i * DD;
        const float* l1g = ln1_g + (size_t)i * DD;
        const float* l1b = ln1_b + (size_t)i * DD;
        const float* l2g = ln2_g + (size_t)i * DD;
        const float* l2b = ln2_b + (size_t)i * DD;
        const float* gw  = gate_w + (size_t)i * NEXP * DD;
        const float* gb  = gate_b + (size_t)i * NEXP;
        const float* w1l = w1 + (size_t)i * NEXP * DD * HHID;
        const float* b1l = b1 + (size_t)i * NEXP * HHID;
        const float* w2l = w2 + (size_t)i * NEXP * HHID * DD;
        const float* b2l = b2 + (size_t)i * NEXP * DD;

        // per-layer weight prep (rotating buffers)
        cvt_bf16<<<(2304*DD/8 + 255)/256, blk, 0, stream>>>(aw, wq_bf, 2304*DD);
        cvt_bf16<<<(DD*DD/8 + 255)/256, blk, 0, stream>>>(ow, wo_bf, DD*DD);
        transpose_cvt<<<dim3(HHID/32, DD/32, NEXP), blk, 0, stream>>>(w1l, w1t, DD, HHID);
        transpose_cvt<<<dim3(DD/32, HHID/32, NEXP), blk, 0, stream>>>(w2l, w2t, HHID, DD);

        ln_kernel<<<MT, blk, 0, stream>>>(h, l1g, l1b, qn);
        gemm_bf16<1><<<dim3(DD/64, 25, 1), blk, 0, stream>>>(
            qn, wq_bf, ab, qb, nullptr, nullptr, nullptr, MT, DD, DD);
        gemm_bf16<1><<<dim3(1536/64, 25, 1), blk, 0, stream>>>(
            h, wq_bf + (size_t)DD * DD, ab + DD, kvb, nullptr, nullptr, nullptr, MT, 1536, DD);
        attn_kernel<<<dim3(SS, 12, BB), blk, 0, stream>>>(qb, kvb, ob);
        gemm_bf16<2><<<dim3(DD/64, 25, 1), blk, 0, stream>>>(
            ob, wo_bf, obias, h, nullptr, nullptr, nullptr, MT, DD, DD);
        ln_kernel<<<MT, blk, 0, stream>>>(h, l2g, l2b, yb);
        zero_cnt<<<1, 64, 0, stream>>>(cnt);
        gate_kernel<<<MT, blk, 0, stream>>>(yb, gw, gb, gv, cnt, idxb);
        gemm_bf16<3><<<dim3(HHID/64, 25, NEXP), blk, 0, stream>>>(
            yb, w1t, b1l, hd, cnt, idxb, nullptr, MT, HHID, DD);
        gemm_bf16<4><<<dim3(DD/64, 25, NEXP), blk, 0, stream>>>(
            hd, w2t, b2l, h, cnt, idxb, gv, MT, DD, HHID);
    }

    head_kernel<<<(BB*1000 + 255)/256, blk, 0, stream>>>(h, head_w, head_b, out);
}

// Round 3
// 2475.078 us; speedup vs baseline: 5.0337x; 2.0864x over previous
//
#include <hip/hip_runtime.h>
#include <math.h>

// MoE ViT forward. bf16-MFMA GEMMs w/ global_load_lds + MFMA attention.
// B=8, S=197, D=768, NH=12, HD=64, E=4, HID=3072, DEPTH=12, NC=1000

#define BB 8
#define SS 197
#define DD 768
#define MT (BB*SS)      // 1576 tokens
#define NPATCH 196
#define MPE (BB*NPATCH) // 1568
#define HHID 3072
#define NEXP 4

typedef __bf16 bf16_t;
typedef bf16_t bf16x8 __attribute__((ext_vector_type(8)));
typedef float  f32x4  __attribute__((ext_vector_type(4)));

__device__ __forceinline__ void gload16(const bf16_t* g, bf16_t* l) {
    __builtin_amdgcn_global_load_lds(
        (const __attribute__((address_space(1))) unsigned int*)g,
        (__attribute__((address_space(3))) unsigned int*)l,
        16, 0, 0);
}

__device__ __forceinline__ bf16x8 cvt8(float4 a, float4 b) {
    bf16x8 o;
    o[0]=(bf16_t)a.x; o[1]=(bf16_t)a.y; o[2]=(bf16_t)a.z; o[3]=(bf16_t)a.w;
    o[4]=(bf16_t)b.x; o[5]=(bf16_t)b.y; o[6]=(bf16_t)b.z; o[7]=(bf16_t)b.w;
    return o;
}

// ---------------- patch gather: Xp[m,k] = x[b,cin, py*16+ph, px*16+pw] (bf16) ----------------
__global__ void gather_patches(const float* __restrict__ x, bf16_t* __restrict__ Xp) {
    int i = blockIdx.x * 256 + threadIdx.x;
    if (i >= MPE * DD) return;
    int k = i % DD;
    int m = i / DD;
    int pw = k & 15, ph = (k >> 4) & 15, cin = k >> 8;
    int px = m % 14, py = (m / 14) % 14, b = m / NPATCH;
    int row = py * 16 + ph, col = px * 16 + pw;
    Xp[i] = (bf16_t)x[((size_t)(b * 3 + cin) * 224 + row) * 224 + col];
}

// ---------------- h init: cls + patches + pos ----------------
__global__ void build_h(const float* __restrict__ pe, const float* __restrict__ patch_b,
                        const float* __restrict__ cls, const float* __restrict__ pos,
                        float* __restrict__ h) {
    int i = blockIdx.x * 256 + threadIdx.x;
    if (i >= MT * DD) return;
    int d = i % DD;
    int s = (i / DD) % SS;
    int b = i / (DD * SS);
    float v;
    if (s == 0) v = cls[d];
    else        v = pe[((size_t)(b * NPATCH) + (s - 1)) * DD + d] + patch_b[d];
    h[i] = v + pos[s * DD + d];
}

// ---------------- fp32 -> bf16 straight convert ----------------
__global__ void cvt_bf16(const float* __restrict__ in, bf16_t* __restrict__ out, int n) {
    int i = (blockIdx.x * 256 + threadIdx.x) * 8;
    if (i >= n) return;
    const float4* p = (const float4*)(in + i);
    *(bf16x8*)(out + i) = cvt8(p[0], p[1]);
}

// ---------------- fp32 [R][C] -> bf16 [C][R] transpose-convert ----------------
__global__ __launch_bounds__(256) void transpose_cvt(const float* __restrict__ in,
                                                     bf16_t* __restrict__ out, int R, int C) {
    int z = blockIdx.z;
    in  += (size_t)z * R * C;
    out += (size_t)z * R * C;
    __shared__ float t[32][33];
    int c0 = blockIdx.x * 32, r0 = blockIdx.y * 32;
    int tx = threadIdx.x & 31, ty = threadIdx.x >> 5;  // 32x8
    #pragma unroll
    for (int i = 0; i < 4; i++)
        t[ty + 8*i][tx] = in[(size_t)(r0 + ty + 8*i) * C + c0 + tx];
    __syncthreads();
    #pragma unroll
    for (int i = 0; i < 4; i++)
        out[(size_t)(c0 + ty + 8*i) * R + r0 + tx] = (bf16_t)t[tx][ty + 8*i];
}

// ---------------- unified bf16-MFMA GEMM, global_load_lds + dbuf prefetch ----------------
// C[M,N] = A[M,K] bf16 @ B[N,K]^T bf16
// MODE 0: fp32 store; 2: fp32 C += v+bias; 3: gather, bf16 store gelu(v+bias);
// MODE 4: gather, fp32 C += (v+bias)*gv; 5: bf16 store v+bias
template<int MODE>
__global__ __launch_bounds__(256) void gemm_bf16(
    const bf16_t* __restrict__ A, const bf16_t* __restrict__ Bw,
    const float* __restrict__ bias, float* __restrict__ C, bf16_t* __restrict__ Cb,
    const int* __restrict__ cnt, const int* __restrict__ idx,
    const float* __restrict__ gv, int M, int N, int K)
{
    constexpr bool GATHER = (MODE == 3 || MODE == 4);
    int z = blockIdx.z;
    int count = GATHER ? cnt[z] : M;
    int m0 = blockIdx.y * 64;
    if (m0 >= count) return;
    int n0 = blockIdx.x * 64;
    Bw += (size_t)z * N * K;
    const float* biasz = bias ? (bias + (size_t)z * N) : nullptr;

    __shared__ bf16_t As[2][64 * 64];
    __shared__ bf16_t Bs[2][64 * 64];
    __shared__ int toks[64];

    int tid = threadIdx.x, lane = tid & 63, w = tid >> 6;
    if (tid < 64) {
        int mm = m0 + tid;
        if (mm > count - 1) mm = count - 1;
        toks[tid] = GATHER ? idx[z * MT + mm] : mm;
    }
    __syncthreads();

    int wm = (w >> 1) * 32, wn = (w & 1) * 32;
    int fr = lane & 15, fs = lane >> 4;

    f32x4 acc[2][2];
    #pragma unroll
    for (int mi = 0; mi < 2; mi++)
        #pragma unroll
        for (int ni = 0; ni < 2; ni++)
            #pragma unroll
            for (int j = 0; j < 4; j++) acc[mi][ni][j] = 0.f;

    int nk = K >> 6;

    #define STAGE(buf, k0)                                                          \
        {                                                                           \
            _Pragma("unroll")                                                       \
            for (int it = 0; it < 2; it++) {                                        \
                int row = 8*(it*4 + w) + (lane >> 3), cc = lane & 7;                \
                const bf16_t* sa = A  + (size_t)toks[row] * K + (k0) + ((cc ^ (row & 7)) << 3); \
                gload16(sa, &As[buf][(it*4 + w) * 512]);                            \
                const bf16_t* sb = Bw + (size_t)(n0 + row) * K + (k0) + ((cc ^ (row & 7)) << 3); \
                gload16(sb, &Bs[buf][(it*4 + w) * 512]);                            \
            }                                                                       \
        }

    STAGE(0, 0);
    __syncthreads();
    int cur = 0;
    for (int t = 0; t < nk; t++) {
        if (t + 1 < nk) STAGE(cur ^ 1, (t + 1) << 6);
        #pragma unroll
        for (int ks = 0; ks < 2; ks++) {
            bf16x8 af[2], bfr[2];
            #pragma unroll
            for (int mi = 0; mi < 2; mi++) {
                int r = wm + mi * 16 + fr;
                af[mi] = *(bf16x8*)&As[cur][r * 64 + (((fs + ks*4) ^ (r & 7)) << 3)];
            }
            #pragma unroll
            for (int ni = 0; ni < 2; ni++) {
                int r = wn + ni * 16 + fr;
                bfr[ni] = *(bf16x8*)&Bs[cur][r * 64 + (((fs + ks*4) ^ (r & 7)) << 3)];
            }
            #pragma unroll
            for (int mi = 0; mi < 2; mi++)
                #pragma unroll
                for (int ni = 0; ni < 2; ni++)
                    acc[mi][ni] = __builtin_amdgcn_mfma_f32_16x16x32_bf16(af[mi], bfr[ni], acc[mi][ni], 0, 0, 0);
        }
        __syncthreads();
        cur ^= 1;
    }
    #undef STAGE

    #pragma unroll
    for (int mi = 0; mi < 2; mi++) {
        #pragma unroll
        for (int j = 0; j < 4; j++) {
            int rr = wm + mi * 16 + fs * 4 + j;
            if (m0 + rr >= count) continue;
            int crow = toks[rr];
            #pragma unroll
            for (int ni = 0; ni < 2; ni++) {
                int col = n0 + wn + ni * 16 + fr;
                float v = acc[mi][ni][j];
                if (MODE >= 2) v += biasz[col];
                if (MODE == 0) C[(size_t)crow * N + col] = v;
                else if (MODE == 2) C[(size_t)crow * N + col] += v;
                else if (MODE == 3) {
                    float g = 0.5f * v * (1.0f + tanhf(0.7978845608028654f * (v + 0.044715f * v * v * v)));
                    Cb[(size_t)crow * N + col] = (bf16_t)g;
                } else if (MODE == 4) {
                    C[(size_t)crow * N + col] += v * gv[crow];
                } else {
                    Cb[(size_t)crow * N + col] = (bf16_t)v;
                }
            }
        }
    }
}

// ---------------- LN1: writes qn bf16 and h bf16 ----------------
__global__ __launch_bounds__(256) void ln1_kernel(const float* __restrict__ x,
                                                  const float* __restrict__ g,
                                                  const float* __restrict__ b,
                                                  bf16_t* __restrict__ qn,
                                                  bf16_t* __restrict__ hb)
{
    int m = blockIdx.x, t = threadIdx.x;
    __shared__ float buf[DD];
    __shared__ float tmp[4];
    float s = 0.f;
    for (int j = t; j < DD; j += 256) { float v = x[(size_t)m*DD + j]; buf[j] = v; s += v; }
    #pragma unroll
    for (int o = 32; o > 0; o >>= 1) s += __shfl_down(s, o);
    if ((t & 63) == 0) tmp[t >> 6] = s;
    __syncthreads();
    float mean = (tmp[0]+tmp[1]+tmp[2]+tmp[3]) * (1.0f/DD);
    float s2 = 0.f;
    for (int j = t; j < DD; j += 256) { float d = buf[j] - mean; s2 += d*d; }
    #pragma unroll
    for (int o = 32; o > 0; o >>= 1) s2 += __shfl_down(s2, o);
    __syncthreads();
    if ((t & 63) == 0) tmp[t >> 6] = s2;
    __syncthreads();
    float var = (tmp[0]+tmp[1]+tmp[2]+tmp[3]) * (1.0f/DD);
    float rs = rsqrtf(var + 1e-5f);
    for (int j = t; j < DD; j += 256) {
        qn[(size_t)m*DD + j] = (bf16_t)((buf[j] - mean) * rs * g[j] + b[j]);
        hb[(size_t)m*DD + j] = (bf16_t)buf[j];
    }
}

// ---------------- LN2 + gate fused: writes y bf16, gv, compaction ----------------
__global__ __launch_bounds__(256) void ln2_gate_kernel(const float* __restrict__ x,
                                                       const float* __restrict__ g,
                                                       const float* __restrict__ b,
                                                       const float* __restrict__ gw,
                                                       const float* __restrict__ gb,
                                                       bf16_t* __restrict__ yb,
                                                       float* __restrict__ gv,
                                                       int* __restrict__ cnt,
                                                       int* __restrict__ idxb)
{
    int m = blockIdx.x, t = threadIdx.x;
    __shared__ float buf[DD];
    __shared__ float tmp[4];
    __shared__ float red[4][4];
    float s = 0.f;
    for (int j = t; j < DD; j += 256) { float v = x[(size_t)m*DD + j]; buf[j] = v; s += v; }
    #pragma unroll
    for (int o = 32; o > 0; o >>= 1) s += __shfl_down(s, o);
    if ((t & 63) == 0) tmp[t >> 6] = s;
    __syncthreads();
    float mean = (tmp[0]+tmp[1]+tmp[2]+tmp[3]) * (1.0f/DD);
    float s2 = 0.f;
    for (int j = t; j < DD; j += 256) { float d = buf[j] - mean; s2 += d*d; }
    #pragma unroll
    for (int o = 32; o > 0; o >>= 1) s2 += __shfl_down(s2, o);
    __syncthreads();
    if ((t & 63) == 0) tmp[t >> 6] = s2;
    __syncthreads();
    float var = (tmp[0]+tmp[1]+tmp[2]+tmp[3]) * (1.0f/DD);
    float rs = rsqrtf(var + 1e-5f);
    float p0 = 0.f, p1 = 0.f, p2 = 0.f, p3 = 0.f;
    for (int j = t; j < DD; j += 256) {
        float y = (buf[j] - mean) * rs * g[j] + b[j];
        yb[(size_t)m*DD + j] = (bf16_t)y;
        p0 += y * gw[j];
        p1 += y * gw[DD + j];
        p2 += y * gw[2*DD + j];
        p3 += y * gw[3*DD + j];
    }
    #pragma unroll
    for (int o = 32; o > 0; o >>= 1) {
        p0 += __shfl_down(p0, o); p1 += __shfl_down(p1, o);
        p2 += __shfl_down(p2, o); p3 += __shfl_down(p3, o);
    }
    if ((t & 63) == 0) { int ww = t >> 6; red[ww][0]=p0; red[ww][1]=p1; red[ww][2]=p2; red[ww][3]=p3; }
    __syncthreads();
    if (t == 0) {
        float l0 = red[0][0]+red[1][0]+red[2][0]+red[3][0] + gb[0];
        float l1 = red[0][1]+red[1][1]+red[2][1]+red[3][1] + gb[1];
        float l2 = red[0][2]+red[1][2]+red[2][2]+red[3][2] + gb[2];
        float l3 = red[0][3]+red[1][3]+red[2][3]+red[3][3] + gb[3];
        int top = 0; float best = l0;
        if (l1 > best) { best = l1; top = 1; }
        if (l2 > best) { best = l2; top = 2; }
        if (l3 > best) { best = l3; top = 3; }
        float Z = __expf(l0-best) + __expf(l1-best) + __expf(l2-best) + __expf(l3-best);
        gv[m] = 1.0f / Z;
        int pos = atomicAdd(&cnt[top], 1);
        idxb[top * MT + pos] = m;
    }
}

// ---------------- MFMA attention: block per (q-tile, head, batch) ----------------
__global__ __launch_bounds__(256) void attn_kernel(const bf16_t* __restrict__ qb,
                                                   const bf16_t* __restrict__ kvb,
                                                   bf16_t* __restrict__ ob)
{
    int qt = blockIdx.x, hh = blockIdx.y, b = blockIdx.z;
    __shared__ bf16_t Qs[64 * 64];
    __shared__ bf16_t Ks[64 * 64];
    __shared__ bf16_t Vt[64 * 72];
    __shared__ float  Sc[64 * 276];
    __shared__ float  linv[64];

    int tid = threadIdx.x, lane = tid & 63, w = tid >> 6;
    int wm = (w >> 1) * 32, wn = (w & 1) * 32;
    int fr = lane & 15, fs = lane >> 4;

    // stage Q tile (64 q rows x 64 d)
    #pragma unroll
    for (int it = 0; it < 2; it++) {
        int row = 8*(it*4 + w) + (lane >> 3), cc = lane & 7;
        int q = qt*64 + row; if (q > SS-1) q = SS-1;
        const bf16_t* src = qb + ((size_t)(b*SS + q))*DD + hh*64 + ((cc ^ (row & 7)) << 3);
        gload16(src, &Qs[(it*4 + w) * 512]);
    }

    // QK^T over 4 k-tiles
    for (int kt = 0; kt < 4; kt++) {
        __syncthreads();
        #pragma unroll
        for (int it = 0; it < 2; it++) {
            int row = 8*(it*4 + w) + (lane >> 3), cc = lane & 7;
            int k = kt*64 + row; if (k > SS-1) k = SS-1;
            const bf16_t* src = kvb + ((size_t)(b*SS + k))*1536 + hh*64 + ((cc ^ (row & 7)) << 3);
            gload16(src, &Ks[(it*4 + w) * 512]);
        }
        __syncthreads();
        f32x4 acc[2][2];
        #pragma unroll
        for (int mi = 0; mi < 2; mi++)
            #pragma unroll
            for (int ni = 0; ni < 2; ni++)
                #pragma unroll
                for (int j = 0; j < 4; j++) acc[mi][ni][j] = 0.f;
        #pragma unroll
        for (int ks = 0; ks < 2; ks++) {
            bf16x8 af[2], bfr[2];
            #pragma unroll
            for (int mi = 0; mi < 2; mi++) {
                int r = wm + mi * 16 + fr;
                af[mi] = *(bf16x8*)&Qs[r * 64 + (((fs + ks*4) ^ (r & 7)) << 3)];
            }
            #pragma unroll
            for (int ni = 0; ni < 2; ni++) {
                int r = wn + ni * 16 + fr;
                bfr[ni] = *(bf16x8*)&Ks[r * 64 + (((fs + ks*4) ^ (r & 7)) << 3)];
            }
            #pragma unroll
            for (int mi = 0; mi < 2; mi++)
                #pragma unroll
                for (int ni = 0; ni < 2; ni++)
                    acc[mi][ni] = __builtin_amdgcn_mfma_f32_16x16x32_bf16(af[mi], bfr[ni], acc[mi][ni], 0, 0, 0);
        }
        #pragma unroll
        for (int mi = 0; mi < 2; mi++)
            #pragma unroll
            for (int j = 0; j < 4; j++) {
                int qr = wm + mi * 16 + fs * 4 + j;
                #pragma unroll
                for (int ni = 0; ni < 2; ni++) {
                    int col = kt*64 + wn + ni * 16 + fr;
                    float v = acc[mi][ni][j] * 0.125f;
                    if (col > SS-1) v = -1e30f;
                    Sc[qr * 276 + col] = v;
                }
            }
    }
    __syncthreads();

    // softmax: 4 threads per row
    {
        int row = tid >> 2, c = tid & 3;
        float m = -1e30f;
        for (int i = c; i < 256; i += 4) m = fmaxf(m, Sc[row * 276 + i]);
        m = fmaxf(m, __shfl_xor(m, 1, 4));
        m = fmaxf(m, __shfl_xor(m, 2, 4));
        float s = 0.f;
        for (int i = c; i < 256; i += 4) {
            float e = __expf(Sc[row * 276 + i] - m);
            Sc[row * 276 + i] = e;
            s += e;
        }
        s += __shfl_xor(s, 1, 4);
        s += __shfl_xor(s, 2, 4);
        if (c == 0) linv[row] = 1.0f / s;
    }

    // PV over 4 k-tiles
    f32x4 pv[2][2];
    #pragma unroll
    for (int mi = 0; mi < 2; mi++)
        #pragma unroll
        for (int ni = 0; ni < 2; ni++)
            #pragma unroll
            for (int j = 0; j < 4; j++) pv[mi][ni][j] = 0.f;

    for (int kt = 0; kt < 4; kt++) {
        __syncthreads();
        {
            int s = tid >> 2, c2 = tid & 3;
            int k = kt*64 + s; if (k > SS-1) k = SS-1;
            const bf16_t* vr = kvb + ((size_t)(b*SS + k))*1536 + 768 + hh*64;
            bf16x8 v0 = *(const bf16x8*)(vr + c2*16);
            bf16x8 v1 = *(const bf16x8*)(vr + c2*16 + 8);
            #pragma unroll
            for (int j = 0; j < 8; j++) {
                Vt[(c2*16 + j) * 72 + s]     = v0[j];
                Vt[(c2*16 + 8 + j) * 72 + s] = v1[j];
            }
        }
        __syncthreads();
        #pragma unroll
        for (int ks = 0; ks < 2; ks++) {
            int s0 = kt*64 + ks*32;
            bf16x8 af[2], bfr[2];
            #pragma unroll
            for (int mi = 0; mi < 2; mi++) {
                int qr = wm + mi * 16 + fr;
                const float* p = &Sc[qr * 276 + s0 + fs * 8];
                af[mi] = cvt8(*(const float4*)p, *(const float4*)(p + 4));
            }
            #pragma unroll
            for (int ni = 0; ni < 2; ni++) {
                int d = wn + ni * 16 + fr;
                bfr[ni] = *(bf16x8*)&Vt[d * 72 + ks*32 + fs*8];
            }
            #pragma unroll
            for (int mi = 0; mi < 2; mi++)
                #pragma unroll
                for (int ni = 0; ni < 2; ni++)
                    pv[mi][ni] = __builtin_amdgcn_mfma_f32_16x16x32_bf16(af[mi], bfr[ni], pv[mi][ni], 0, 0, 0);
        }
    }

    #pragma unroll
    for (int mi = 0; mi < 2; mi++)
        #pragma unroll
        for (int j = 0; j < 4; j++) {
            int qr = wm + mi * 16 + fs * 4 + j;
            int q = qt*64 + qr;
            if (q > SS-1) continue;
            float il = linv[qr];
            #pragma unroll
            for (int ni = 0; ni < 2; ni++) {
                int d = wn + ni * 16 + fr;
                ob[((size_t)(b*SS + q))*DD + hh*64 + d] = (bf16_t)(pv[mi][ni][j] * il);
            }
        }
}

// ---------------- zero expert counters ----------------
__global__ void zero_cnt(int* cnt) { if (threadIdx.x < NEXP) cnt[threadIdx.x] = 0; }

// ---------------- classifier head ----------------
__global__ void head_kernel(const float* __restrict__ h, const float* __restrict__ hw,
                            const float* __restrict__ hb, float* __restrict__ out)
{
    int i = blockIdx.x * 256 + threadIdx.x;
    if (i >= BB * 1000) return;
    int b = i & 7, n = i >> 3;
    const float4* hr = (const float4*)(h + (size_t)(b * SS) * DD);
    const float4* wr = (const float4*)(hw + (size_t)n * DD);
    float s = 0.f;
    #pragma unroll 4
    for (int k = 0; k < DD/4; k++) {
        float4 a = hr[k], wv = wr[k];
        s += a.x*wv.x + a.y*wv.y + a.z*wv.z + a.w*wv.w;
    }
    out[b * 1000 + n] = s + hb[n];
}

extern "C" void kernel_launch(void* const* d_in, const int* in_sizes, int n_in,
                              void* d_out, int out_size, void* d_ws, size_t ws_size,
                              hipStream_t stream) {
    const float* x          = (const float*)d_in[0];
    const float* patch_w    = (const float*)d_in[1];
    const float* patch_b    = (const float*)d_in[2];
    const float* cls_token  = (const float*)d_in[3];
    const float* pos_embed  = (const float*)d_in[4];
    const float* ln1_g      = (const float*)d_in[5];
    const float* ln1_b      = (const float*)d_in[6];
    const float* ln2_g      = (const float*)d_in[7];
    const float* ln2_b      = (const float*)d_in[8];
    const float* attn_in_w  = (const float*)d_in[9];
    const float* attn_in_b  = (const float*)d_in[10];
    const float* attn_out_w = (const float*)d_in[11];
    const float* attn_out_b = (const float*)d_in[12];
    const float* gate_w     = (const float*)d_in[13];
    const float* gate_b     = (const float*)d_in[14];
    const float* w1         = (const float*)d_in[15];
    const float* b1         = (const float*)d_in[16];
    const float* w2         = (const float*)d_in[17];
    const float* b2         = (const float*)d_in[18];
    const float* head_w     = (const float*)d_in[19];
    const float* head_b     = (const float*)d_in[20];
    float* out = (float*)d_out;

    char* wsb = (char*)d_ws;
    auto alloc = [&](size_t bytes) { char* p = wsb; wsb += (bytes + 63) & ~63ULL; return p; };
    bf16_t* Xp    = (bf16_t*)alloc((size_t)MPE * DD * 2);
    float*  pe    = (float*) alloc((size_t)MPE * DD * 4);
    float*  h     = (float*) alloc((size_t)MT * DD * 4);
    bf16_t* qn_bf = (bf16_t*)alloc((size_t)MT * DD * 2);
    bf16_t* h_bf  = (bf16_t*)alloc((size_t)MT * DD * 2);
    bf16_t* qb_bf = (bf16_t*)alloc((size_t)MT * DD * 2);
    bf16_t* kv_bf = (bf16_t*)alloc((size_t)MT * 1536 * 2);
    bf16_t* ob_bf = (bf16_t*)alloc((size_t)MT * DD * 2);
    bf16_t* yb_bf = (bf16_t*)alloc((size_t)MT * DD * 2);
    bf16_t* hd_bf = (bf16_t*)alloc((size_t)MT * HHID * 2);
    float*  gv    = (float*) alloc((size_t)MT * 4);
    int*    cnt   = (int*)   alloc(64 * 4);
    int*    idxb  = (int*)   alloc((size_t)NEXP * MT * 4);
    bf16_t* wq_bf = (bf16_t*)alloc((size_t)2304 * DD * 2);
    bf16_t* wo_bf = (bf16_t*)alloc((size_t)DD * DD * 2);
    bf16_t* w1t   = (bf16_t*)alloc((size_t)NEXP * DD * HHID * 2);
    bf16_t* w2t   = (bf16_t*)alloc((size_t)NEXP * DD * HHID * 2);
    bf16_t* pw_bf = (bf16_t*)alloc((size_t)DD * DD * 2);

    dim3 blk(256);

    cvt_bf16<<<(DD*DD/8 + 255)/256, blk, 0, stream>>>(patch_w, pw_bf, DD*DD);
    gather_patches<<<(MPE*DD + 255)/256, blk, 0, stream>>>(x, Xp);
    gemm_bf16<0><<<dim3(DD/64, (MPE+63)/64, 1), blk, 0, stream>>>(
        Xp, pw_bf, nullptr, pe, nullptr, nullptr, nullptr, nullptr, MPE, DD, DD);
    build_h<<<(MT*DD + 255)/256, blk, 0, stream>>>(pe, patch_b, cls_token, pos_embed, h);

    for (int i = 0; i < 12; i++) {
        const float* aw    = attn_in_w  + (size_t)i * 2304 * DD;
        const float* ab    = attn_in_b  + (size_t)i * 2304;
        const float* ow    = attn_out_w + (size_t)i * DD * DD;
        const float* obias = attn_out_b + (size_t)i * DD;
        const float* l1g = ln1_g + (size_t)i * DD;
        const float* l1b = ln1_b + (size_t)i * DD;
        const float* l2g = ln2_g + (size_t)i * DD;
        const float* l2b = ln2_b + (size_t)i * DD;
        const float* gw  = gate_w + (size_t)i * NEXP * DD;
        const float* gb  = gate_b + (size_t)i * NEXP;
        const float* w1l = w1 + (size_t)i * NEXP * DD * HHID;
        const float* b1l = b1 + (size_t)i * NEXP * HHID;
        const float* w2l = w2 + (size_t)i * NEXP * HHID * DD;
        const float* b2l = b2 + (size_t)i * NEXP * DD;

        cvt_bf16<<<(2304*DD/8 + 255)/256, blk, 0, stream>>>(aw, wq_bf, 2304*DD);
        cvt_bf16<<<(DD*DD/8 + 255)/256, blk, 0, stream>>>(ow, wo_bf, DD*DD);
        transpose_cvt<<<dim3(HHID/32, DD/32, NEXP), blk, 0, stream>>>(w1l, w1t, DD, HHID);
        transpose_cvt<<<dim3(DD/32, HHID/32, NEXP), blk, 0, stream>>>(w2l, w2t, HHID, DD);

        ln1_kernel<<<MT, blk, 0, stream>>>(h, l1g, l1b, qn_bf, h_bf);
        gemm_bf16<5><<<dim3(DD/64, 25, 1), blk, 0, stream>>>(
            qn_bf, wq_bf, ab, nullptr, qb_bf, nullptr, nullptr, nullptr, MT, DD, DD);
        gemm_bf16<5><<<dim3(1536/64, 25, 1), blk, 0, stream>>>(
            h_bf, wq_bf + (size_t)DD * DD, ab + DD, nullptr, kv_bf, nullptr, nullptr, nullptr, MT, 1536, DD);
        attn_kernel<<<dim3(4, 12, BB), blk, 0, stream>>>(qb_bf, kv_bf, ob_bf);
        gemm_bf16<2><<<dim3(DD/64, 25, 1), blk, 0, stream>>>(
            ob_bf, wo_bf, obias, h, nullptr, nullptr, nullptr, nullptr, MT, DD, DD);
        zero_cnt<<<1, 64, 0, stream>>>(cnt);
        ln2_gate_kernel<<<MT, blk, 0, stream>>>(h, l2g, l2b, gw, gb, yb_bf, gv, cnt, idxb);
        gemm_bf16<3><<<dim3(HHID/64, 25, NEXP), blk, 0, stream>>>(
            yb_bf, w1t, b1l, nullptr, hd_bf, cnt, idxb, nullptr, MT, HHID, DD);
        gemm_bf16<4><<<dim3(DD/64, 25, NEXP), blk, 0, stream>>>(
            hd_bf, w2t, b2l, h, nullptr, cnt, idxb, gv, MT, DD, HHID);
    }

    head_kernel<<<(BB*1000 + 255)/256, blk, 0, stream>>>(h, head_w, head_b, out);
}